// Round 3
// baseline (258.255 us; speedup 1.0000x reference)
//
#include <hip/hip_runtime.h>
#include <stdint.h>

// Problem constants (B,S,D,H,E) = (2,2048,1024,16,64)
#define B_  2
#define S_  2048
#define D_  1024
#define H_  16
#define E_  64
#define BH_ 32
#define M_  4096  // B*S

typedef __bf16 bf16x8 __attribute__((ext_vector_type(8)));
typedef float  f32x4  __attribute__((ext_vector_type(4)));
typedef unsigned short u16;

__device__ __forceinline__ u16 f2bf(float f) {
  uint32_t u = __builtin_bit_cast(uint32_t, f);
  u = (u + 0x7FFFu + ((u >> 16) & 1u)) >> 16;  // round-nearest-even
  return (u16)u;
}

__device__ __forceinline__ bf16x8 load_frag(const u16* p) {
  uint4 v = *(const uint4*)p;
  return __builtin_bit_cast(bf16x8, v);
}

// ---------------------------------------------------------------------------
// Transpose + fp32->bf16: in [batch][R][C] f32 -> out [batch][C][R] bf16
// block (32,8), grid (C/32, R/32, batch)
// ---------------------------------------------------------------------------
__global__ __launch_bounds__(256) void transpose_cvt(
    const float* __restrict__ in, u16* __restrict__ out, int R, int C)
{
  __shared__ float tile[32][33];
  const int b = blockIdx.z;
  in  += (size_t)b * R * C;
  out += (size_t)b * R * C;
  const int c0 = blockIdx.x * 32, r0 = blockIdx.y * 32;
  const int tx = threadIdx.x, ty = threadIdx.y;
#pragma unroll
  for (int j = 0; j < 32; j += 8)
    tile[ty + j][tx] = in[(size_t)(r0 + ty + j) * C + c0 + tx];
  __syncthreads();
#pragma unroll
  for (int j = 0; j < 32; j += 8)
    out[(size_t)(c0 + ty + j) * R + r0 + tx] = f2bf(tile[tx][ty + j]);
}

// ---------------------------------------------------------------------------
// q,k,v fp32 -> bf16 concat [3][M][D]. grid (n/1024, 3) block 256
// ---------------------------------------------------------------------------
__global__ __launch_bounds__(256) void cvt3_bf16(
    const float* __restrict__ a, const float* __restrict__ b,
    const float* __restrict__ c, u16* __restrict__ out, int n)
{
  const float* src = blockIdx.y == 0 ? a : (blockIdx.y == 1 ? b : c);
  u16* dst = out + (size_t)blockIdx.y * n;
  int i = (blockIdx.x * 256 + threadIdx.x) * 4;
  if (i < n) {
    float4 v = *(const float4*)(src + i);
    ushort4 o;
    o.x = f2bf(v.x); o.y = f2bf(v.y); o.z = f2bf(v.z); o.w = f2bf(v.w);
    *(ushort4*)(dst + i) = o;
  }
}

// ---------------------------------------------------------------------------
// 128x128 tile bf16 GEMM, BK=64, 4 waves (each 64x64), padded LDS (no bank
// conflicts), A [M][K] bf16, Bt [N][K] bf16 (i.e. C = A * Bt^T).
// MODE 0: fused QKV projection. N = 3*1024 panels; epilogue adds per-third
//         bias and scatters qh [BH][S][E], kh [BH][S][E], vT [BH][E][S] bf16.
// MODE 1: out projection. epilogue adds bias + residual, writes fp32 x.
// ---------------------------------------------------------------------------
template<int MODE>
__global__ __launch_bounds__(256) void gemm128(
    const u16* __restrict__ A, const u16* __restrict__ Bt,
    const float* __restrict__ b0, const float* __restrict__ b1,
    const float* __restrict__ b2, const float* __restrict__ resid,
    u16* __restrict__ outQ, u16* __restrict__ outK, u16* __restrict__ outV,
    float* __restrict__ outX)
{
  __shared__ __align__(16) u16 As[128][72];
  __shared__ __align__(16) u16 Bs[128][72];
  const int K  = D_;
  const int m0 = blockIdx.y * 128;
  const int n0 = blockIdx.x * 128;
  const int tid = threadIdx.x;
  const int w = tid >> 6, l = tid & 63;
  const int wr = w >> 1, wc = w & 1;
  const int lr = l & 15, lg = l >> 4;

  const u16* Ause = A;
  const u16* Buse = Bt;
  const float* bias = b0;
  int third = 0, nloc = n0;
  if (MODE == 0) {
    third = n0 >> 10;
    nloc  = n0 & 1023;
    Ause  = A  + (size_t)third * M_ * D_;
    Buse  = Bt + (size_t)third * D_ * D_;
    bias  = third == 0 ? b0 : (third == 1 ? b1 : b2);
  }

  f32x4 acc[4][4] = {};

  for (int k0 = 0; k0 < K; k0 += 64) {
    __syncthreads();
#pragma unroll
    for (int j = 0; j < 4; ++j) {
      int f = (tid + j * 256) * 8;
      int r = f >> 6, c = f & 63;
      *(uint4*)(&As[r][c]) = *(const uint4*)(Ause + (size_t)(m0 + r) * K + k0 + c);
      *(uint4*)(&Bs[r][c]) = *(const uint4*)(Buse + (size_t)(nloc + r) * K + k0 + c);
    }
    __syncthreads();
#pragma unroll
    for (int kc = 0; kc < 2; ++kc) {
      bf16x8 af[4], bfr[4];
#pragma unroll
      for (int mi = 0; mi < 4; ++mi)
        af[mi] = load_frag(&As[wr * 64 + mi * 16 + lr][kc * 32 + lg * 8]);
#pragma unroll
      for (int ni = 0; ni < 4; ++ni)
        bfr[ni] = load_frag(&Bs[wc * 64 + ni * 16 + lr][kc * 32 + lg * 8]);
#pragma unroll
      for (int mi = 0; mi < 4; ++mi)
#pragma unroll
        for (int ni = 0; ni < 4; ++ni)
          acc[mi][ni] = __builtin_amdgcn_mfma_f32_16x16x32_bf16(
              af[mi], bfr[ni], acc[mi][ni], 0, 0, 0);
    }
  }

  const int rbase = m0 + wr * 64;
  const int cbase = nloc + wc * 64;
#pragma unroll
  for (int mi = 0; mi < 4; ++mi) {
#pragma unroll
    for (int ni = 0; ni < 4; ++ni) {
      const int col = cbase + ni * 16 + lr;
      const float bv = bias[col];
      if (MODE == 0) {
        const int h = col >> 6, e = col & 63;
        if (third < 2) {
          u16* dst = third == 0 ? outQ : outK;
#pragma unroll
          for (int i = 0; i < 4; ++i) {
            int row = rbase + mi * 16 + lg * 4 + i;
            int bb = row >> 11, s = row & (S_ - 1);
            dst[((size_t)(bb * H_ + h) * S_ + s) * E_ + e] = f2bf(acc[mi][ni][i] + bv);
          }
        } else {
          int s0 = rbase + mi * 16 + lg * 4;
          int bb = s0 >> 11, srel = s0 & (S_ - 1);
          ushort4 o;
          o.x = f2bf(acc[mi][ni][0] + bv);
          o.y = f2bf(acc[mi][ni][1] + bv);
          o.z = f2bf(acc[mi][ni][2] + bv);
          o.w = f2bf(acc[mi][ni][3] + bv);
          *(ushort4*)(outV + ((size_t)(bb * H_ + h) * E_ + e) * S_ + srel) = o;
        }
      } else {
#pragma unroll
        for (int i = 0; i < 4; ++i) {
          int row = rbase + mi * 16 + lg * 4 + i;
          size_t idx = (size_t)row * D_ + col;
          outX[idx] = acc[mi][ni][i] + bv + resid[idx];
        }
      }
    }
  }
}

// ---------------------------------------------------------------------------
// Flash attention. grid (S/64, BH), block 256 (4 waves x 16 q-rows).
// qh,kh: [BH][S][E] bf16; vT: [BH][E][S] bf16; out cat: [B*S][H*E] bf16.
// Online softmax; P round-trips through per-wave padded LDS into A-frag form.
// ---------------------------------------------------------------------------
__global__ __launch_bounds__(256) void attn_kernel(
    const u16* __restrict__ qh, const u16* __restrict__ kh,
    const u16* __restrict__ vT, u16* __restrict__ cat)
{
  __shared__ __align__(16) u16 Ks[64][72];
  __shared__ __align__(16) u16 Vs[64][72];
  __shared__ __align__(16) u16 Ps[4][16][72];
  const int bh = blockIdx.y;
  const int q0 = blockIdx.x * 64;
  const int tid = threadIdx.x;
  const int w = tid >> 6, l = tid & 63;
  const int lr = l & 15, lg = l >> 4;

  const u16* qbase = qh + ((size_t)bh * S_ + q0 + w * 16) * E_;
  bf16x8 aq[2];
  aq[0] = load_frag(qbase + (size_t)lr * E_ + lg * 8);
  aq[1] = load_frag(qbase + (size_t)lr * E_ + 32 + lg * 8);

  f32x4 oacc[4] = {};
  float mrow[4], lrow[4];
#pragma unroll
  for (int i = 0; i < 4; ++i) { mrow[i] = -1e30f; lrow[i] = 0.f; }

  for (int t0 = 0; t0 < S_; t0 += 64) {
    __syncthreads();  // previous iter's LDS reads done before restage
#pragma unroll
    for (int j = 0; j < 2; ++j) {
      int f = (tid + j * 256) * 8;
      int r = f >> 6, c = f & 63;
      *(uint4*)(&Ks[r][c]) = *(const uint4*)(kh + ((size_t)bh * S_ + t0 + r) * E_ + c);
      *(uint4*)(&Vs[r][c]) = *(const uint4*)(vT + ((size_t)bh * E_ + r) * S_ + t0 + c);
    }
    __syncthreads();

    // S = (Q K^T) / 8
    f32x4 sacc[4] = {};
#pragma unroll
    for (int kc = 0; kc < 2; ++kc) {
#pragma unroll
      for (int tt = 0; tt < 4; ++tt) {
        bf16x8 bk = load_frag(&Ks[tt * 16 + lr][kc * 32 + lg * 8]);
        sacc[tt] = __builtin_amdgcn_mfma_f32_16x16x32_bf16(aq[kc], bk, sacc[tt], 0, 0, 0);
      }
    }
    float pm[4];
#pragma unroll
    for (int i = 0; i < 4; ++i) pm[i] = mrow[i];
#pragma unroll
    for (int tt = 0; tt < 4; ++tt)
#pragma unroll
      for (int i = 0; i < 4; ++i) {
        sacc[tt][i] *= 0.125f;
        pm[i] = fmaxf(pm[i], sacc[tt][i]);
      }
#pragma unroll
    for (int d = 1; d < 16; d <<= 1)
#pragma unroll
      for (int i = 0; i < 4; ++i)
        pm[i] = fmaxf(pm[i], __shfl_xor(pm[i], d));

    float alpha[4], rs[4];
#pragma unroll
    for (int i = 0; i < 4; ++i) {
      alpha[i] = exp2f((mrow[i] - pm[i]) * 1.44269504f);
      mrow[i] = pm[i];
      rs[i] = 0.f;
    }
#pragma unroll
    for (int tt = 0; tt < 4; ++tt)
#pragma unroll
      for (int i = 0; i < 4; ++i) {
        float pv = exp2f((sacc[tt][i] - mrow[i]) * 1.44269504f);
        sacc[tt][i] = pv;
        rs[i] += pv;
      }
#pragma unroll
    for (int d = 1; d < 16; d <<= 1)
#pragma unroll
      for (int i = 0; i < 4; ++i)
        rs[i] += __shfl_xor(rs[i], d);
#pragma unroll
    for (int i = 0; i < 4; ++i) lrow[i] = lrow[i] * alpha[i] + rs[i];
#pragma unroll
    for (int et = 0; et < 4; ++et)
#pragma unroll
      for (int i = 0; i < 4; ++i) oacc[et][i] *= alpha[i];

    // P (D-layout) -> per-wave LDS -> A-frag layout
#pragma unroll
    for (int tt = 0; tt < 4; ++tt)
#pragma unroll
      for (int i = 0; i < 4; ++i)
        Ps[w][lg * 4 + i][lr + tt * 16] = f2bf(sacc[tt][i]);
    __syncthreads();

#pragma unroll
    for (int kc = 0; kc < 2; ++kc) {
      bf16x8 pa = load_frag(&Ps[w][lr][kc * 32 + lg * 8]);
#pragma unroll
      for (int et = 0; et < 4; ++et) {
        bf16x8 bv = load_frag(&Vs[et * 16 + lr][kc * 32 + lg * 8]);
        oacc[et] = __builtin_amdgcn_mfma_f32_16x16x32_bf16(pa, bv, oacc[et], 0, 0, 0);
      }
    }
  }

  const int bb = bh >> 4, h = bh & 15;
#pragma unroll
  for (int et = 0; et < 4; ++et)
#pragma unroll
    for (int i = 0; i < 4; ++i) {
      int s = q0 + w * 16 + lg * 4 + i;
      int col = h * E_ + et * 16 + lr;
      cat[((size_t)bb * S_ + s) * D_ + col] = f2bf(oacc[et][i] / lrow[i]);
    }
}

// ---------------------------------------------------------------------------
// In-place LayerNorm over rows of x [M][D] fp32. grid M, block 256.
// ---------------------------------------------------------------------------
__global__ __launch_bounds__(256) void layernorm_kernel(
    float* __restrict__ x, const float* __restrict__ gamma,
    const float* __restrict__ beta)
{
  __shared__ float red[8];
  const int row = blockIdx.x;
  float* p = x + (size_t)row * D_;
  const int tid = threadIdx.x;
  float4 v = *(const float4*)(p + tid * 4);
  float s  = v.x + v.y + v.z + v.w;
  float sq = v.x * v.x + v.y * v.y + v.z * v.z + v.w * v.w;
#pragma unroll
  for (int d = 1; d < 64; d <<= 1) {
    s  += __shfl_xor(s, d);
    sq += __shfl_xor(sq, d);
  }
  const int w = tid >> 6, l = tid & 63;
  if (l == 0) { red[w] = s; red[4 + w] = sq; }
  __syncthreads();
  float S1 = red[0] + red[1] + red[2] + red[3];
  float S2 = red[4] + red[5] + red[6] + red[7];
  float mu  = S1 * (1.f / D_);
  float var = S2 * (1.f / D_) - mu * mu;
  float rinv = rsqrtf(var + 1e-5f);
  float4 g  = *(const float4*)(gamma + tid * 4);
  float4 bt = *(const float4*)(beta + tid * 4);
  float4 o;
  o.x = (v.x - mu) * rinv * g.x + bt.x;
  o.y = (v.y - mu) * rinv * g.y + bt.y;
  o.z = (v.z - mu) * rinv * g.z + bt.z;
  o.w = (v.w - mu) * rinv * g.w + bt.w;
  *(float4*)(p + tid * 4) = o;
}

// ---------------------------------------------------------------------------
extern "C" void kernel_launch(void* const* d_in, const int* in_sizes, int n_in,
                              void* d_out, int out_size, void* d_ws, size_t ws_size,
                              hipStream_t stream) {
  (void)in_sizes; (void)n_in; (void)out_size; (void)ws_size;
  const float* q     = (const float*)d_in[0];
  const float* k     = (const float*)d_in[1];
  const float* v     = (const float*)d_in[2];
  const float* Wq    = (const float*)d_in[3];
  const float* bq    = (const float*)d_in[4];
  const float* Wk    = (const float*)d_in[5];
  const float* bk    = (const float*)d_in[6];
  const float* Wv    = (const float*)d_in[7];
  const float* bv    = (const float*)d_in[8];
  const float* Wo    = (const float*)d_in[9];
  const float* bo    = (const float*)d_in[10];
  const float* gamma = (const float*)d_in[11];
  const float* beta  = (const float*)d_in[12];

  char* ws = (char*)d_ws;
  // Workspace layout (total ~56 MB):
  u16* qkv_bf = (u16*)ws;                      // [3][4096][1024] bf16 = 24 MB
  u16* Wt     = (u16*)(ws + 25165824);         // [3][1024][1024] bf16 =  6 MB
  u16* WoT    = (u16*)(ws + 31457280);         // [1024][1024]   bf16 =  2 MB
  u16* qhb    = (u16*)(ws + 33554432);         // [BH][S][64]    bf16 =  8 MB
  u16* khb    = (u16*)(ws + 41943040);         // [BH][S][64]    bf16 =  8 MB
  u16* vTb    = (u16*)(ws + 50331648);         // [BH][64][S]    bf16 =  8 MB
  u16* cat    = qkv_bf;                        // reuse q_bf region (free by then)
  float* x    = (float*)d_out;                 // pre-LN fp32, LN in-place

  dim3 tb(32, 8);
  // Wq/Wk/Wv: per-head [D][E] -> [E][D]  (=> Bt rows n=h*E+e over k=d)
  transpose_cvt<<<dim3(2, 32, 16), tb, 0, stream>>>(Wq, Wt,               1024, 64);
  transpose_cvt<<<dim3(2, 32, 16), tb, 0, stream>>>(Wk, Wt + 1048576,     1024, 64);
  transpose_cvt<<<dim3(2, 32, 16), tb, 0, stream>>>(Wv, Wt + 2097152,     1024, 64);
  // Wo [H*E][D] -> [D][H*E]
  transpose_cvt<<<dim3(32, 32, 1), tb, 0, stream>>>(Wo, WoT,              1024, 1024);
  cvt3_bf16<<<dim3(4096, 3), 256, 0, stream>>>(q, k, v, qkv_bf, M_ * D_);

  gemm128<0><<<dim3(24, 32), 256, 0, stream>>>(qkv_bf, Wt, bq, bk, bv, nullptr,
                                               qhb, khb, vTb, nullptr);
  attn_kernel<<<dim3(32, 32), 256, 0, stream>>>(qhb, khb, vTb, cat);
  gemm128<1><<<dim3(8, 32), 256, 0, stream>>>(cat, WoT, bo, nullptr, nullptr, q,
                                              nullptr, nullptr, nullptr, x);
  layernorm_kernel<<<4096, 256, 0, stream>>>(x, gamma, beta);
}

// Round 4
// 206.922 us; speedup vs baseline: 1.2481x; 1.2481x over previous
//
#include <hip/hip_runtime.h>
#include <stdint.h>

// Problem constants (B,S,D,H,E) = (2,2048,1024,16,64)
#define B_  2
#define S_  2048
#define D_  1024
#define H_  16
#define E_  64
#define BH_ 32
#define M_  4096  // B*S

typedef __bf16 bf16x8 __attribute__((ext_vector_type(8)));
typedef float  f32x4  __attribute__((ext_vector_type(4)));
typedef unsigned short u16;

__device__ __forceinline__ u16 f2bf(float f) {
  uint32_t u = __builtin_bit_cast(uint32_t, f);
  u = (u + 0x7FFFu + ((u >> 16) & 1u)) >> 16;  // round-nearest-even
  return (u16)u;
}

__device__ __forceinline__ uint32_t pack_bf2(float lo, float hi) {
  return (uint32_t)f2bf(lo) | ((uint32_t)f2bf(hi) << 16);
}

__device__ __forceinline__ bf16x8 load_frag(const u16* p) {
  uint4 v = *(const uint4*)p;
  return __builtin_bit_cast(bf16x8, v);
}

// ---------------------------------------------------------------------------
// Transpose + fp32->bf16: in [batch][R][C] f32 -> out [batch][C][R] bf16
// block (32,8), grid (C/32, R/32, batch)
// ---------------------------------------------------------------------------
__global__ __launch_bounds__(256) void transpose_cvt(
    const float* __restrict__ in, u16* __restrict__ out, int R, int C)
{
  __shared__ float tile[32][33];
  const int b = blockIdx.z;
  in  += (size_t)b * R * C;
  out += (size_t)b * R * C;
  const int c0 = blockIdx.x * 32, r0 = blockIdx.y * 32;
  const int tx = threadIdx.x, ty = threadIdx.y;
#pragma unroll
  for (int j = 0; j < 32; j += 8)
    tile[ty + j][tx] = in[(size_t)(r0 + ty + j) * C + c0 + tx];
  __syncthreads();
#pragma unroll
  for (int j = 0; j < 32; j += 8)
    out[(size_t)(c0 + ty + j) * R + r0 + tx] = f2bf(tile[tx][ty + j]);
}

// ---------------------------------------------------------------------------
// q,k,v fp32 -> bf16 concat [3][M][D]. grid (n/1024, 3) block 256
// ---------------------------------------------------------------------------
__global__ __launch_bounds__(256) void cvt3_bf16(
    const float* __restrict__ a, const float* __restrict__ b,
    const float* __restrict__ c, u16* __restrict__ out, int n)
{
  const float* src = blockIdx.y == 0 ? a : (blockIdx.y == 1 ? b : c);
  u16* dst = out + (size_t)blockIdx.y * n;
  int i = (blockIdx.x * 256 + threadIdx.x) * 4;
  if (i < n) {
    float4 v = *(const float4*)(src + i);
    ushort4 o;
    o.x = f2bf(v.x); o.y = f2bf(v.y); o.z = f2bf(v.z); o.w = f2bf(v.w);
    *(ushort4*)(dst + i) = o;
  }
}

// ---------------------------------------------------------------------------
// 128x128 tile bf16 GEMM, BK=64, 4 waves (each 64x64), padded LDS,
// A [M][K] bf16, Bt [N][K] bf16 (i.e. C = A * Bt^T).  (unchanged from R0)
// ---------------------------------------------------------------------------
template<int MODE>
__global__ __launch_bounds__(256) void gemm128(
    const u16* __restrict__ A, const u16* __restrict__ Bt,
    const float* __restrict__ b0, const float* __restrict__ b1,
    const float* __restrict__ b2, const float* __restrict__ resid,
    u16* __restrict__ outQ, u16* __restrict__ outK, u16* __restrict__ outV,
    float* __restrict__ outX)
{
  __shared__ __align__(16) u16 As[128][72];
  __shared__ __align__(16) u16 Bs[128][72];
  const int K  = D_;
  const int m0 = blockIdx.y * 128;
  const int n0 = blockIdx.x * 128;
  const int tid = threadIdx.x;
  const int w = tid >> 6, l = tid & 63;
  const int wr = w >> 1, wc = w & 1;
  const int lr = l & 15, lg = l >> 4;

  const u16* Ause = A;
  const u16* Buse = Bt;
  const float* bias = b0;
  int third = 0, nloc = n0;
  if (MODE == 0) {
    third = n0 >> 10;
    nloc  = n0 & 1023;
    Ause  = A  + (size_t)third * M_ * D_;
    Buse  = Bt + (size_t)third * D_ * D_;
    bias  = third == 0 ? b0 : (third == 1 ? b1 : b2);
  }

  f32x4 acc[4][4] = {};

  for (int k0 = 0; k0 < K; k0 += 64) {
    __syncthreads();
#pragma unroll
    for (int j = 0; j < 4; ++j) {
      int f = (tid + j * 256) * 8;
      int r = f >> 6, c = f & 63;
      *(uint4*)(&As[r][c]) = *(const uint4*)(Ause + (size_t)(m0 + r) * K + k0 + c);
      *(uint4*)(&Bs[r][c]) = *(const uint4*)(Buse + (size_t)(nloc + r) * K + k0 + c);
    }
    __syncthreads();
#pragma unroll
    for (int kc = 0; kc < 2; ++kc) {
      bf16x8 af[4], bfr[4];
#pragma unroll
      for (int mi = 0; mi < 4; ++mi)
        af[mi] = load_frag(&As[wr * 64 + mi * 16 + lr][kc * 32 + lg * 8]);
#pragma unroll
      for (int ni = 0; ni < 4; ++ni)
        bfr[ni] = load_frag(&Bs[wc * 64 + ni * 16 + lr][kc * 32 + lg * 8]);
#pragma unroll
      for (int mi = 0; mi < 4; ++mi)
#pragma unroll
        for (int ni = 0; ni < 4; ++ni)
          acc[mi][ni] = __builtin_amdgcn_mfma_f32_16x16x32_bf16(
              af[mi], bfr[ni], acc[mi][ni], 0, 0, 0);
    }
  }

  const int rbase = m0 + wr * 64;
  const int cbase = nloc + wc * 64;
#pragma unroll
  for (int mi = 0; mi < 4; ++mi) {
#pragma unroll
    for (int ni = 0; ni < 4; ++ni) {
      const int col = cbase + ni * 16 + lr;
      const float bv = bias[col];
      if (MODE == 0) {
        const int h = col >> 6, e = col & 63;
        if (third < 2) {
          u16* dst = third == 0 ? outQ : outK;
#pragma unroll
          for (int i = 0; i < 4; ++i) {
            int row = rbase + mi * 16 + lg * 4 + i;
            int bb = row >> 11, s = row & (S_ - 1);
            dst[((size_t)(bb * H_ + h) * S_ + s) * E_ + e] = f2bf(acc[mi][ni][i] + bv);
          }
        } else {
          int s0 = rbase + mi * 16 + lg * 4;
          int bb = s0 >> 11, srel = s0 & (S_ - 1);
          ushort4 o;
          o.x = f2bf(acc[mi][ni][0] + bv);
          o.y = f2bf(acc[mi][ni][1] + bv);
          o.z = f2bf(acc[mi][ni][2] + bv);
          o.w = f2bf(acc[mi][ni][3] + bv);
          *(ushort4*)(outV + ((size_t)(bb * H_ + h) * E_ + e) * S_ + srel) = o;
        }
      } else {
#pragma unroll
        for (int i = 0; i < 4; ++i) {
          int row = rbase + mi * 16 + lg * 4 + i;
          size_t idx = (size_t)row * D_ + col;
          outX[idx] = acc[mi][ni][i] + bv + resid[idx];
        }
      }
    }
  }
}

// ---------------------------------------------------------------------------
// Flash attention v2 — swapped QK^T, in-register softmax, no P LDS round-trip.
// grid (S/64, BH), block 256 (4 waves x 16 queries).
// qh,kh: [BH][S][E] bf16; vT: [BH][E][S] bf16; out cat: [B*S][H*E] bf16.
//
// Per wave: 16 queries. S^T = mfma(A=K, B=Q): lane (lr=l&15 -> query col,
// lg=l>>4) holds S[key=16*tt+4*lg+i][query=lr]. Softmax per query = 15 local
// ops + 2 shfl_xor (d=16,32) over the 4-lane group. P^T stays in registers;
// redistribution to the PV B-fragment (keys 32*kc+8*lg+j for query lr) pulls
// packed bf16x2 words from lanes srcA=lr+32*(lg&1), srcB=srcA+16, register
// tt=2*kc+(lg>>1).  O^T = mfma(A=V^T (Vs as stored), B=P^T).
// ---------------------------------------------------------------------------
__global__ __launch_bounds__(256) void attn_kernel(
    const u16* __restrict__ qh, const u16* __restrict__ kh,
    const u16* __restrict__ vT, u16* __restrict__ cat)
{
  __shared__ __align__(16) u16 Ks[64][72];
  __shared__ __align__(16) u16 Vs[64][72];
  const int bh = blockIdx.y;
  const int q0 = blockIdx.x * 64;
  const int tid = threadIdx.x;
  const int w = tid >> 6, l = tid & 63;
  const int lr = l & 15, lg = l >> 4;

  // Q as B-fragment: lane reads Q[query=lr][k-chunk lg*8], kc halves of E=64
  const u16* qbase = qh + ((size_t)bh * S_ + q0 + w * 16) * E_;
  bf16x8 bq_[2];
  bq_[0] = load_frag(qbase + (size_t)lr * E_ + lg * 8);
  bq_[1] = load_frag(qbase + (size_t)lr * E_ + 32 + lg * 8);

  f32x4 oacc[4] = {};           // O^T: lane holds e = 16*et + 4*lg + i, q = lr
  float m_ = -1e30f, l_ = 0.f;  // per-query running max / denom (group-redundant)

  const int srcA = lr + ((l & 16) << 1);  // lane lr + 16*(2*(lg&1))
  const int srcB = srcA + 16;
  const int sel  = (l >> 5) & 1;          // lg>>1

  for (int t0 = 0; t0 < S_; t0 += 64) {
    __syncthreads();  // previous iter's LDS reads done before restage
#pragma unroll
    for (int j = 0; j < 2; ++j) {
      int f = (tid + j * 256) * 8;
      int r = f >> 6, c = f & 63;
      *(uint4*)(&Ks[r][c]) = *(const uint4*)(kh + ((size_t)bh * S_ + t0 + r) * E_ + c);
      *(uint4*)(&Vs[r][c]) = *(const uint4*)(vT + ((size_t)bh * E_ + r) * S_ + t0 + c);
    }
    __syncthreads();

    // S^T = K * Q^T, scaled by 1/8
    f32x4 sacc[4] = {};
#pragma unroll
    for (int kc = 0; kc < 2; ++kc) {
#pragma unroll
      for (int tt = 0; tt < 4; ++tt) {
        bf16x8 ak = load_frag(&Ks[tt * 16 + lr][kc * 32 + lg * 8]);
        sacc[tt] = __builtin_amdgcn_mfma_f32_16x16x32_bf16(ak, bq_[kc], sacc[tt], 0, 0, 0);
      }
    }

    // online softmax, per-query (all 16 lane-local values belong to query lr)
    float pm = m_;
#pragma unroll
    for (int tt = 0; tt < 4; ++tt)
#pragma unroll
      for (int i = 0; i < 4; ++i) {
        sacc[tt][i] *= 0.125f;
        pm = fmaxf(pm, sacc[tt][i]);
      }
    pm = fmaxf(pm, __shfl_xor(pm, 16));
    pm = fmaxf(pm, __shfl_xor(pm, 32));

    float alpha = exp2f((m_ - pm) * 1.44269504f);
    m_ = pm;
    float rs = 0.f;
#pragma unroll
    for (int tt = 0; tt < 4; ++tt)
#pragma unroll
      for (int i = 0; i < 4; ++i) {
        float pv = exp2f((sacc[tt][i] - pm) * 1.44269504f);
        sacc[tt][i] = pv;
        rs += pv;
      }
    rs += __shfl_xor(rs, 16);
    rs += __shfl_xor(rs, 32);
    l_ = l_ * alpha + rs;
#pragma unroll
    for (int et = 0; et < 4; ++et)
#pragma unroll
      for (int i = 0; i < 4; ++i) oacc[et][i] *= alpha;

    // pack P to bf16 pairs: pk[tt][0] = keys {4g+0,4g+1}, pk[tt][1] = {4g+2,4g+3}
    uint32_t pk[4][2];
#pragma unroll
    for (int tt = 0; tt < 4; ++tt) {
      pk[tt][0] = pack_bf2(sacc[tt][0], sacc[tt][1]);
      pk[tt][1] = pack_bf2(sacc[tt][2], sacc[tt][3]);
    }

    // redistribute P^T into PV B-fragments and multiply-accumulate
#pragma unroll
    for (int kc = 0; kc < 2; ++kc) {
      const int t0i = 2 * kc, t1i = 2 * kc + 1;
      uint32_t a00 = (uint32_t)__shfl((int)pk[t0i][0], srcA);
      uint32_t a01 = (uint32_t)__shfl((int)pk[t0i][1], srcA);
      uint32_t a10 = (uint32_t)__shfl((int)pk[t1i][0], srcA);
      uint32_t a11 = (uint32_t)__shfl((int)pk[t1i][1], srcA);
      uint32_t b00 = (uint32_t)__shfl((int)pk[t0i][0], srcB);
      uint32_t b01 = (uint32_t)__shfl((int)pk[t0i][1], srcB);
      uint32_t b10 = (uint32_t)__shfl((int)pk[t1i][0], srcB);
      uint32_t b11 = (uint32_t)__shfl((int)pk[t1i][1], srcB);
      uint4 pw;
      pw.x = sel ? a10 : a00;
      pw.y = sel ? a11 : a01;
      pw.z = sel ? b10 : b00;
      pw.w = sel ? b11 : b01;
      bf16x8 pb = __builtin_bit_cast(bf16x8, pw);
#pragma unroll
      for (int et = 0; et < 4; ++et) {
        bf16x8 av = load_frag(&Vs[et * 16 + lr][kc * 32 + lg * 8]);
        oacc[et] = __builtin_amdgcn_mfma_f32_16x16x32_bf16(av, pb, oacc[et], 0, 0, 0);
      }
    }
  }

  // epilogue: O^T -> cat[b*S + q][h*64 + e], 4 contiguous e per reg
  const int bb = bh >> 4, h = bh & 15;
  const float inv = 1.f / l_;
  const size_t rowbase = ((size_t)bb * S_ + q0 + w * 16 + lr) * D_ + h * E_;
#pragma unroll
  for (int et = 0; et < 4; ++et) {
    ushort4 o;
    o.x = f2bf(oacc[et][0] * inv);
    o.y = f2bf(oacc[et][1] * inv);
    o.z = f2bf(oacc[et][2] * inv);
    o.w = f2bf(oacc[et][3] * inv);
    *(ushort4*)(&cat[rowbase + et * 16 + lg * 4]) = o;
  }
}

// ---------------------------------------------------------------------------
// In-place LayerNorm over rows of x [M][D] fp32. grid M, block 256.
// ---------------------------------------------------------------------------
__global__ __launch_bounds__(256) void layernorm_kernel(
    float* __restrict__ x, const float* __restrict__ gamma,
    const float* __restrict__ beta)
{
  __shared__ float red[8];
  const int row = blockIdx.x;
  float* p = x + (size_t)row * D_;
  const int tid = threadIdx.x;
  float4 v = *(const float4*)(p + tid * 4);
  float s  = v.x + v.y + v.z + v.w;
  float sq = v.x * v.x + v.y * v.y + v.z * v.z + v.w * v.w;
#pragma unroll
  for (int d = 1; d < 64; d <<= 1) {
    s  += __shfl_xor(s, d);
    sq += __shfl_xor(sq, d);
  }
  const int w = tid >> 6, l = tid & 63;
  if (l == 0) { red[w] = s; red[4 + w] = sq; }
  __syncthreads();
  float S1 = red[0] + red[1] + red[2] + red[3];
  float S2 = red[4] + red[5] + red[6] + red[7];
  float mu  = S1 * (1.f / D_);
  float var = S2 * (1.f / D_) - mu * mu;
  float rinv = rsqrtf(var + 1e-5f);
  float4 g  = *(const float4*)(gamma + tid * 4);
  float4 bt = *(const float4*)(beta + tid * 4);
  float4 o;
  o.x = (v.x - mu) * rinv * g.x + bt.x;
  o.y = (v.y - mu) * rinv * g.y + bt.y;
  o.z = (v.z - mu) * rinv * g.z + bt.z;
  o.w = (v.w - mu) * rinv * g.w + bt.w;
  *(float4*)(p + tid * 4) = o;
}

// ---------------------------------------------------------------------------
extern "C" void kernel_launch(void* const* d_in, const int* in_sizes, int n_in,
                              void* d_out, int out_size, void* d_ws, size_t ws_size,
                              hipStream_t stream) {
  (void)in_sizes; (void)n_in; (void)out_size; (void)ws_size;
  const float* q     = (const float*)d_in[0];
  const float* k     = (const float*)d_in[1];
  const float* v     = (const float*)d_in[2];
  const float* Wq    = (const float*)d_in[3];
  const float* bq    = (const float*)d_in[4];
  const float* Wk    = (const float*)d_in[5];
  const float* bk    = (const float*)d_in[6];
  const float* Wv    = (const float*)d_in[7];
  const float* bv    = (const float*)d_in[8];
  const float* Wo    = (const float*)d_in[9];
  const float* bo    = (const float*)d_in[10];
  const float* gamma = (const float*)d_in[11];
  const float* beta  = (const float*)d_in[12];

  char* ws = (char*)d_ws;
  // Workspace layout (total ~56 MB):
  u16* qkv_bf = (u16*)ws;                      // [3][4096][1024] bf16 = 24 MB
  u16* Wt     = (u16*)(ws + 25165824);         // [3][1024][1024] bf16 =  6 MB
  u16* WoT    = (u16*)(ws + 31457280);         // [1024][1024]   bf16 =  2 MB
  u16* qhb    = (u16*)(ws + 33554432);         // [BH][S][64]    bf16 =  8 MB
  u16* khb    = (u16*)(ws + 41943040);         // [BH][S][64]    bf16 =  8 MB
  u16* vTb    = (u16*)(ws + 50331648);         // [BH][64][S]    bf16 =  8 MB
  u16* cat    = qkv_bf;                        // reuse q_bf region (free by then)
  float* x    = (float*)d_out;                 // pre-LN fp32, LN in-place

  dim3 tb(32, 8);
  // Wq/Wk/Wv: per-head [D][E] -> [E][D]  (=> Bt rows n=h*E+e over k=d)
  transpose_cvt<<<dim3(2, 32, 16), tb, 0, stream>>>(Wq, Wt,               1024, 64);
  transpose_cvt<<<dim3(2, 32, 16), tb, 0, stream>>>(Wk, Wt + 1048576,     1024, 64);
  transpose_cvt<<<dim3(2, 32, 16), tb, 0, stream>>>(Wv, Wt + 2097152,     1024, 64);
  // Wo [H*E][D] -> [D][H*E]
  transpose_cvt<<<dim3(32, 32, 1), tb, 0, stream>>>(Wo, WoT,              1024, 1024);
  cvt3_bf16<<<dim3(4096, 3), 256, 0, stream>>>(q, k, v, qkv_bf, M_ * D_);

  gemm128<0><<<dim3(24, 32), 256, 0, stream>>>(qkv_bf, Wt, bq, bk, bv, nullptr,
                                               qhb, khb, vTb, nullptr);
  attn_kernel<<<dim3(32, 32), 256, 0, stream>>>(qhb, khb, vTb, cat);
  gemm128<1><<<dim3(8, 32), 256, 0, stream>>>(cat, WoT, bo, nullptr, nullptr, q,
                                              nullptr, nullptr, nullptr, x);
  layernorm_kernel<<<4096, 256, 0, stream>>>(x, gamma, beta);
}

// Round 5
// 184.896 us; speedup vs baseline: 1.3968x; 1.1191x over previous
//
#include <hip/hip_runtime.h>
#include <stdint.h>

// Problem constants (B,S,D,H,E) = (2,2048,1024,16,64)
#define B_  2
#define S_  2048
#define D_  1024
#define H_  16
#define E_  64
#define BH_ 32
#define M_  4096  // B*S

typedef __bf16 bf16x8 __attribute__((ext_vector_type(8)));
typedef float  f32x4  __attribute__((ext_vector_type(4)));
typedef float  f32x16 __attribute__((ext_vector_type(16)));
typedef unsigned short u16;

// Q pre-scale: 1/sqrt(E) * log2(e), folded into qh at projection epilogue
#define QSCALE 0.180336880f

__device__ __forceinline__ u16 f2bf(float f) {
  uint32_t u = __builtin_bit_cast(uint32_t, f);
  u = (u + 0x7FFFu + ((u >> 16) & 1u)) >> 16;  // round-nearest-even
  return (u16)u;
}

// pack two floats to bf16x2 word via compiler casts (lowers to v_cvt_pk_bf16_f32)
__device__ __forceinline__ uint32_t pkbf(float lo, float hi) {
  __bf16 a = (__bf16)lo, b = (__bf16)hi;
  return (uint32_t)__builtin_bit_cast(u16, a) |
         ((uint32_t)__builtin_bit_cast(u16, b) << 16);
}

__device__ __forceinline__ bf16x8 load_frag(const u16* p) {
  uint4 v = *(const uint4*)p;
  return __builtin_bit_cast(bf16x8, v);
}

// ---------------------------------------------------------------------------
// Transpose + fp32->bf16: in [batch][R][C] f32 -> out [batch][C][R] bf16
// ---------------------------------------------------------------------------
__global__ __launch_bounds__(256) void transpose_cvt(
    const float* __restrict__ in, u16* __restrict__ out, int R, int C)
{
  __shared__ float tile[32][33];
  const int b = blockIdx.z;
  in  += (size_t)b * R * C;
  out += (size_t)b * R * C;
  const int c0 = blockIdx.x * 32, r0 = blockIdx.y * 32;
  const int tx = threadIdx.x, ty = threadIdx.y;
#pragma unroll
  for (int j = 0; j < 32; j += 8)
    tile[ty + j][tx] = in[(size_t)(r0 + ty + j) * C + c0 + tx];
  __syncthreads();
#pragma unroll
  for (int j = 0; j < 32; j += 8)
    out[(size_t)(c0 + ty + j) * R + r0 + tx] = f2bf(tile[tx][ty + j]);
}

// ---------------------------------------------------------------------------
// q,k,v fp32 -> bf16 concat [3][M][D]. grid (n/1024, 3) block 256
// ---------------------------------------------------------------------------
__global__ __launch_bounds__(256) void cvt3_bf16(
    const float* __restrict__ a, const float* __restrict__ b,
    const float* __restrict__ c, u16* __restrict__ out, int n)
{
  const float* src = blockIdx.y == 0 ? a : (blockIdx.y == 1 ? b : c);
  u16* dst = out + (size_t)blockIdx.y * n;
  int i = (blockIdx.x * 256 + threadIdx.x) * 4;
  if (i < n) {
    float4 v = *(const float4*)(src + i);
    ushort4 o;
    o.x = f2bf(v.x); o.y = f2bf(v.y); o.z = f2bf(v.z); o.w = f2bf(v.w);
    *(ushort4*)(dst + i) = o;
  }
}

// ---------------------------------------------------------------------------
// 128x128 tile bf16 GEMM, BK=64, 4 waves, padded LDS. C = A * Bt^T.
// MODE 0: fused QKV projection; Q third is additionally scaled by QSCALE
//         (folds softmax 1/sqrt(E) and log2(e) into Q -> attn works in exp2
//         domain). Scatters qh/kh [BH][S][E] and vT [BH][E][S] bf16.
// MODE 1: out projection + bias + residual -> fp32 x.
// ---------------------------------------------------------------------------
template<int MODE>
__global__ __launch_bounds__(256) void gemm128(
    const u16* __restrict__ A, const u16* __restrict__ Bt,
    const float* __restrict__ b0, const float* __restrict__ b1,
    const float* __restrict__ b2, const float* __restrict__ resid,
    u16* __restrict__ outQ, u16* __restrict__ outK, u16* __restrict__ outV,
    float* __restrict__ outX)
{
  __shared__ __align__(16) u16 As[128][72];
  __shared__ __align__(16) u16 Bs[128][72];
  const int K  = D_;
  const int m0 = blockIdx.y * 128;
  const int n0 = blockIdx.x * 128;
  const int tid = threadIdx.x;
  const int w = tid >> 6, l = tid & 63;
  const int wr = w >> 1, wc = w & 1;
  const int lr = l & 15, lg = l >> 4;

  const u16* Ause = A;
  const u16* Buse = Bt;
  const float* bias = b0;
  int third = 0, nloc = n0;
  if (MODE == 0) {
    third = n0 >> 10;
    nloc  = n0 & 1023;
    Ause  = A  + (size_t)third * M_ * D_;
    Buse  = Bt + (size_t)third * D_ * D_;
    bias  = third == 0 ? b0 : (third == 1 ? b1 : b2);
  }

  f32x4 acc[4][4] = {};

  for (int k0 = 0; k0 < K; k0 += 64) {
    __syncthreads();
#pragma unroll
    for (int j = 0; j < 4; ++j) {
      int f = (tid + j * 256) * 8;
      int r = f >> 6, c = f & 63;
      *(uint4*)(&As[r][c]) = *(const uint4*)(Ause + (size_t)(m0 + r) * K + k0 + c);
      *(uint4*)(&Bs[r][c]) = *(const uint4*)(Buse + (size_t)(nloc + r) * K + k0 + c);
    }
    __syncthreads();
#pragma unroll
    for (int kc = 0; kc < 2; ++kc) {
      bf16x8 af[4], bfr[4];
#pragma unroll
      for (int mi = 0; mi < 4; ++mi)
        af[mi] = load_frag(&As[wr * 64 + mi * 16 + lr][kc * 32 + lg * 8]);
#pragma unroll
      for (int ni = 0; ni < 4; ++ni)
        bfr[ni] = load_frag(&Bs[wc * 64 + ni * 16 + lr][kc * 32 + lg * 8]);
#pragma unroll
      for (int mi = 0; mi < 4; ++mi)
#pragma unroll
        for (int ni = 0; ni < 4; ++ni)
          acc[mi][ni] = __builtin_amdgcn_mfma_f32_16x16x32_bf16(
              af[mi], bfr[ni], acc[mi][ni], 0, 0, 0);
    }
  }

  const int rbase = m0 + wr * 64;
  const int cbase = nloc + wc * 64;
#pragma unroll
  for (int mi = 0; mi < 4; ++mi) {
#pragma unroll
    for (int ni = 0; ni < 4; ++ni) {
      const int col = cbase + ni * 16 + lr;
      const float bv = bias[col];
      if (MODE == 0) {
        const int h = col >> 6, e = col & 63;
        if (third < 2) {
          u16* dst = third == 0 ? outQ : outK;
          const float sc = third == 0 ? QSCALE : 1.f;
#pragma unroll
          for (int i = 0; i < 4; ++i) {
            int row = rbase + mi * 16 + lg * 4 + i;
            int bb = row >> 11, s = row & (S_ - 1);
            dst[((size_t)(bb * H_ + h) * S_ + s) * E_ + e] =
                f2bf((acc[mi][ni][i] + bv) * sc);
          }
        } else {
          int s0 = rbase + mi * 16 + lg * 4;
          int bb = s0 >> 11, srel = s0 & (S_ - 1);
          ushort4 o;
          o.x = f2bf(acc[mi][ni][0] + bv);
          o.y = f2bf(acc[mi][ni][1] + bv);
          o.z = f2bf(acc[mi][ni][2] + bv);
          o.w = f2bf(acc[mi][ni][3] + bv);
          *(ushort4*)(outV + ((size_t)(bb * H_ + h) * E_ + e) * S_ + srel) = o;
        }
      } else {
#pragma unroll
        for (int i = 0; i < 4; ++i) {
          int row = rbase + mi * 16 + lg * 4 + i;
          size_t idx = (size_t)row * D_ + col;
          outX[idx] = acc[mi][ni][i] + bv + resid[idx];
        }
      }
    }
  }
}

// ---------------------------------------------------------------------------
// Flash attention v3 — 32x32x16 MFMA swapped structure, 32 queries/wave.
// grid (S/128, BH), block 256 (4 waves x 32 queries).
// qh (pre-scaled by QSCALE), kh: [BH][S][E] bf16; vT: [BH][E][S] bf16.
//
// S^T = mfma32(A=K, B=Q^T): lane (q=l&31, h=l>>5) holds
//   S[key=(reg&3)+8*(reg>>2)+4h+32*kt][query=q] for kt=0,1 (64 keys/iter).
// Softmax per query: 31 local fmax/add + ONE shfl_xor(32).
// P^T -> PV B-frag (key=16*kb+8h+j): own regs give half the keys, the
// partner lane (xor 32) gives the other half: per 16-key frag, pack 4 words,
// exchange 2 via shfl_xor(32), arrange by h.  O^T = mfma32(A=V^T, B=P^T).
// ---------------------------------------------------------------------------
__global__ __launch_bounds__(256, 2) void attn_kernel(
    const u16* __restrict__ qh, const u16* __restrict__ kh,
    const u16* __restrict__ vT, u16* __restrict__ cat)
{
  __shared__ __align__(16) u16 Ks[64][72];
  __shared__ __align__(16) u16 Vs[64][72];
  const int bh = blockIdx.y;
  const int q0 = blockIdx.x * 128;
  const int tid = threadIdx.x;
  const int w = tid >> 6, l = tid & 63;
  const int ql = l & 31;            // query column
  const int h  = l >> 5;            // lane half
  const int qg = q0 + w * 32 + ql;  // global query row

  // Q as B-fragments: 4 K-steps of 16, lane k-chunk = 8*h
  const u16* qrow = qh + ((size_t)bh * S_ + qg) * E_;
  bf16x8 bq_[4];
#pragma unroll
  for (int es = 0; es < 4; ++es)
    bq_[es] = load_frag(qrow + es * 16 + h * 8);

  f32x16 oacc[2] = {};  // O^T e-tiles: e=(reg&3)+8*(reg>>2)+4h+32*eb, q=ql
  float m_ = -1e30f, l_ = 0.f;

  for (int t0 = 0; t0 < S_; t0 += 64) {
    __syncthreads();
#pragma unroll
    for (int j = 0; j < 2; ++j) {
      int f = (tid + j * 256) * 8;
      int r = f >> 6, c = f & 63;
      *(uint4*)(&Ks[r][c]) = *(const uint4*)(kh + ((size_t)bh * S_ + t0 + r) * E_ + c);
      *(uint4*)(&Vs[r][c]) = *(const uint4*)(vT + ((size_t)bh * E_ + r) * S_ + t0 + c);
    }
    __syncthreads();

    // S^T = K * Q^T (already in exp2 domain via QSCALE)
    f32x16 sacc[2] = {};
#pragma unroll
    for (int kt = 0; kt < 2; ++kt)
#pragma unroll
      for (int es = 0; es < 4; ++es) {
        bf16x8 ak = load_frag(&Ks[kt * 32 + ql][es * 16 + h * 8]);
        sacc[kt] = __builtin_amdgcn_mfma_f32_32x32x16_bf16(ak, bq_[es], sacc[kt], 0, 0, 0);
      }

    // online softmax (per query; partner lane holds the other 32 keys)
    float pm = m_;
#pragma unroll
    for (int kt = 0; kt < 2; ++kt)
#pragma unroll
      for (int i = 0; i < 16; ++i) pm = fmaxf(pm, sacc[kt][i]);
    pm = fmaxf(pm, __shfl_xor(pm, 32));

    float alpha = exp2f(m_ - pm);
    m_ = pm;
    float rs = 0.f;
#pragma unroll
    for (int kt = 0; kt < 2; ++kt)
#pragma unroll
      for (int i = 0; i < 16; ++i) {
        float pv = exp2f(sacc[kt][i] - pm);
        sacc[kt][i] = pv;
        rs += pv;
      }
    rs += __shfl_xor(rs, 32);
    l_ = l_ * alpha + rs;
#pragma unroll
    for (int eb = 0; eb < 2; ++eb)
#pragma unroll
      for (int i = 0; i < 16; ++i) oacc[eb][i] *= alpha;

    // PV: for each 16-key fragment, assemble P^T B-frag and accumulate
#pragma unroll
    for (int kt = 0; kt < 2; ++kt) {
#pragma unroll
      for (int c2 = 0; c2 < 2; ++c2) {
        // pack own regs 8*c2 .. 8*c2+7 (keys (reg&3)+8*(reg>>2)+4h within frag)
        uint32_t A0 = pkbf(sacc[kt][8 * c2 + 0], sacc[kt][8 * c2 + 1]);
        uint32_t A1 = pkbf(sacc[kt][8 * c2 + 2], sacc[kt][8 * c2 + 3]);
        uint32_t B0 = pkbf(sacc[kt][8 * c2 + 4], sacc[kt][8 * c2 + 5]);
        uint32_t B1 = pkbf(sacc[kt][8 * c2 + 6], sacc[kt][8 * c2 + 7]);
        // partner (dest half h^1) needs regs 8c2+4*(h^1)..+3 of OUR sacc:
        // h=0 sends B (regs +4..7), h=1 sends A (regs +0..3)
        uint32_t s0 = h ? A0 : B0;
        uint32_t s1 = h ? A1 : B1;
        uint32_t r0 = (uint32_t)__shfl_xor((int)s0, 32);
        uint32_t r1 = (uint32_t)__shfl_xor((int)s1, 32);
        // B-frag words: j0-3 from h_src=0 lane's regs 8c2+4h..; j4-7 from h_src=1
        uint4 pw;
        pw.x = h ? r0 : A0;
        pw.y = h ? r1 : A1;
        pw.z = h ? B0 : r0;
        pw.w = h ? B1 : r1;
        bf16x8 pb = __builtin_bit_cast(bf16x8, pw);
        const int kcol = (kt * 2 + c2) * 16 + h * 8;
#pragma unroll
        for (int eb = 0; eb < 2; ++eb) {
          bf16x8 av = load_frag(&Vs[eb * 32 + ql][kcol]);
          oacc[eb] = __builtin_amdgcn_mfma_f32_32x32x16_bf16(av, pb, oacc[eb], 0, 0, 0);
        }
      }
    }
  }

  // epilogue: O^T -> cat[b*S + q][head*64 + e]; e = i + 8g + 4h + 32eb
  const int bb = bh >> 4, hh = bh & 15;
  const float inv = 1.f / l_;
  const size_t rowbase = ((size_t)bb * S_ + qg) * D_ + hh * E_;
#pragma unroll
  for (int eb = 0; eb < 2; ++eb)
#pragma unroll
    for (int g = 0; g < 4; ++g) {
      ushort4 o;
      o.x = f2bf(oacc[eb][4 * g + 0] * inv);
      o.y = f2bf(oacc[eb][4 * g + 1] * inv);
      o.z = f2bf(oacc[eb][4 * g + 2] * inv);
      o.w = f2bf(oacc[eb][4 * g + 3] * inv);
      *(ushort4*)(&cat[rowbase + eb * 32 + g * 8 + h * 4]) = o;
    }
}

// ---------------------------------------------------------------------------
// In-place LayerNorm over rows of x [M][D] fp32. grid M, block 256.
// ---------------------------------------------------------------------------
__global__ __launch_bounds__(256) void layernorm_kernel(
    float* __restrict__ x, const float* __restrict__ gamma,
    const float* __restrict__ beta)
{
  __shared__ float red[8];
  const int row = blockIdx.x;
  float* p = x + (size_t)row * D_;
  const int tid = threadIdx.x;
  float4 v = *(const float4*)(p + tid * 4);
  float s  = v.x + v.y + v.z + v.w;
  float sq = v.x * v.x + v.y * v.y + v.z * v.z + v.w * v.w;
#pragma unroll
  for (int d = 1; d < 64; d <<= 1) {
    s  += __shfl_xor(s, d);
    sq += __shfl_xor(sq, d);
  }
  const int w = tid >> 6, l = tid & 63;
  if (l == 0) { red[w] = s; red[4 + w] = sq; }
  __syncthreads();
  float S1 = red[0] + red[1] + red[2] + red[3];
  float S2 = red[4] + red[5] + red[6] + red[7];
  float mu  = S1 * (1.f / D_);
  float var = S2 * (1.f / D_) - mu * mu;
  float rinv = rsqrtf(var + 1e-5f);
  float4 g  = *(const float4*)(gamma + tid * 4);
  float4 bt = *(const float4*)(beta + tid * 4);
  float4 o;
  o.x = (v.x - mu) * rinv * g.x + bt.x;
  o.y = (v.y - mu) * rinv * g.y + bt.y;
  o.z = (v.z - mu) * rinv * g.z + bt.z;
  o.w = (v.w - mu) * rinv * g.w + bt.w;
  *(float4*)(p + tid * 4) = o;
}

// ---------------------------------------------------------------------------
extern "C" void kernel_launch(void* const* d_in, const int* in_sizes, int n_in,
                              void* d_out, int out_size, void* d_ws, size_t ws_size,
                              hipStream_t stream) {
  (void)in_sizes; (void)n_in; (void)out_size; (void)ws_size;
  const float* q     = (const float*)d_in[0];
  const float* k     = (const float*)d_in[1];
  const float* v     = (const float*)d_in[2];
  const float* Wq    = (const float*)d_in[3];
  const float* bq    = (const float*)d_in[4];
  const float* Wk    = (const float*)d_in[5];
  const float* bk    = (const float*)d_in[6];
  const float* Wv    = (const float*)d_in[7];
  const float* bv    = (const float*)d_in[8];
  const float* Wo    = (const float*)d_in[9];
  const float* bo    = (const float*)d_in[10];
  const float* gamma = (const float*)d_in[11];
  const float* beta  = (const float*)d_in[12];

  char* ws = (char*)d_ws;
  u16* qkv_bf = (u16*)ws;                      // [3][4096][1024] bf16 = 24 MB
  u16* Wt     = (u16*)(ws + 25165824);         // [3][1024][1024] bf16 =  6 MB
  u16* WoT    = (u16*)(ws + 31457280);         // [1024][1024]   bf16 =  2 MB
  u16* qhb    = (u16*)(ws + 33554432);         // [BH][S][64]    bf16 =  8 MB
  u16* khb    = (u16*)(ws + 41943040);         // [BH][S][64]    bf16 =  8 MB
  u16* vTb    = (u16*)(ws + 50331648);         // [BH][64][S]    bf16 =  8 MB
  u16* cat    = qkv_bf;                        // reuse (free by then)
  float* x    = (float*)d_out;                 // pre-LN fp32, LN in-place

  dim3 tb(32, 8);
  transpose_cvt<<<dim3(2, 32, 16), tb, 0, stream>>>(Wq, Wt,               1024, 64);
  transpose_cvt<<<dim3(2, 32, 16), tb, 0, stream>>>(Wk, Wt + 1048576,     1024, 64);
  transpose_cvt<<<dim3(2, 32, 16), tb, 0, stream>>>(Wv, Wt + 2097152,     1024, 64);
  transpose_cvt<<<dim3(32, 32, 1), tb, 0, stream>>>(Wo, WoT,              1024, 1024);
  cvt3_bf16<<<dim3(4096, 3), 256, 0, stream>>>(q, k, v, qkv_bf, M_ * D_);

  gemm128<0><<<dim3(24, 32), 256, 0, stream>>>(qkv_bf, Wt, bq, bk, bv, nullptr,
                                               qhb, khb, vTb, nullptr);
  attn_kernel<<<dim3(16, 32), 256, 0, stream>>>(qhb, khb, vTb, cat);
  gemm128<1><<<dim3(8, 32), 256, 0, stream>>>(cat, WoT, bo, nullptr, nullptr, q,
                                              nullptr, nullptr, nullptr, x);
  layernorm_kernel<<<4096, 256, 0, stream>>>(x, gamma, beta);
}